// Round 1
// baseline (230.002 us; speedup 1.0000x reference)
//
#include <hip/hip_runtime.h>

// Problem constants (fixed by setup_inputs)
constexpr int kC     = 21;
constexpr int kHW    = 512 * 512;        // 262144
constexpr int kB     = 8;
constexpr int kN     = kB * kHW;         // 2,097,152 pixels
constexpr int kQuads = kN / 4;           // 524,288 float4-groups
constexpr int kBlock = 256;
constexpr int kGrid  = kQuads / kBlock;  // 2048 blocks

// Native clang vector types — __builtin_nontemporal_load requires these
// (HIP's float4/int4 are structs and are rejected).
typedef float fvec4 __attribute__((ext_vector_type(4)));
typedef int   ivec4 __attribute__((ext_vector_type(4)));

// One thread = 4 consecutive pixels (same b, consecutive hw).
// Two-pass softmax entirely in registers: all 21 channel float4s loaded
// up-front (independent, one waitcnt), then pure-VALU max-tree +
// single-exp-per-channel sum. Only x_t is tracked through the loop
// (1 cmp + 1 cndmask per channel); pt recomputed as exp(logpt) in the
// epilogue.
//
// R0 change: NO atomicAdd. 2048 same-address device-scope atomics from 8
// non-coherent XCDs serialize at ~100-300ns each (~150-300us tail) — the
// prime suspect for 241.8us vs the ~30us HBM roofline. Each block now
// writes its partial to a distinct d_ws slot; a 1-block kernel reduces.
__global__ __launch_bounds__(kBlock) void fl_main(const float* __restrict__ x,
                                                  const int* __restrict__ tgt,
                                                  float* __restrict__ part) {
    const int gid = blockIdx.x * kBlock + threadIdx.x;   // quad index
    const int b   = gid >> 16;                           // gid / 65536
    const int hw4 = gid & 0xFFFF;

    const float* xb = x + (size_t)b * ((size_t)kC * kHW) + (size_t)hw4 * 4;

    // targets: pixel linear index p0 = gid*4
    ivec4 t4 = __builtin_nontemporal_load(
        reinterpret_cast<const ivec4*>(tgt + (size_t)gid * 4));

    // Load all 21 channels (4 pixels each) into registers. Streaming,
    // zero reuse -> nontemporal.
    fvec4 v[kC];
#pragma unroll
    for (int c = 0; c < kC; ++c) {
        v[c] = __builtin_nontemporal_load(
            reinterpret_cast<const fvec4*>(xb + (size_t)c * kHW));
    }

    float loss = 0.f;
#pragma unroll
    for (int p = 0; p < 4; ++p) {
        const int t = (t4[p] == 255) ? 0 : t4[p];   // remap 255->0 (fidelity)

        // max over channels
        float m = v[0][p];
#pragma unroll
        for (int c = 1; c < kC; ++c) m = fmaxf(m, v[c][p]);

        // sum of exps; track x_t with one select per channel
        float s = 0.f, xt = v[0][p];
#pragma unroll
        for (int c = 0; c < kC; ++c) {
            const float xv = v[c][p];
            s += __expf(xv - m);
            if (c == t) xt = xv;
        }

        const float logpt = xt - m - __logf(s);
        const float pt    = __expf(logpt);
        const float om    = 1.f - pt;
        loss += om * om * (-logpt);
    }
    loss *= (1.0f / (float)kN);   // prescale so the partial sum IS the mean

    // wave(64) shuffle reduction
#pragma unroll
    for (int off = 32; off > 0; off >>= 1)
        loss += __shfl_down(loss, off, 64);

    __shared__ float ws[kBlock / 64];
    const int lane = threadIdx.x & 63;
    const int wid  = threadIdx.x >> 6;
    if (lane == 0) ws[wid] = loss;
    __syncthreads();
    if (threadIdx.x == 0) {
        // contention-free partial store (distinct slot per block)
        part[blockIdx.x] = ws[0] + ws[1] + ws[2] + ws[3];
    }
}

// 1 block x 256 threads: sum the 2048 partials (8 floats/thread, fvec4 x2),
// write the final mean with a plain store (overwrites the 0xAA poison, so
// no memset dispatch is needed at all).
__global__ __launch_bounds__(kBlock) void fl_reduce(const float* __restrict__ part,
                                                    float* __restrict__ out) {
    const int t = threadIdx.x;
    const fvec4 a = *reinterpret_cast<const fvec4*>(part + (size_t)t * 8);
    const fvec4 b = *reinterpret_cast<const fvec4*>(part + (size_t)t * 8 + 4);
    float s = (a[0] + a[1] + a[2] + a[3]) + (b[0] + b[1] + b[2] + b[3]);

#pragma unroll
    for (int off = 32; off > 0; off >>= 1)
        s += __shfl_down(s, off, 64);

    __shared__ float ws[kBlock / 64];
    const int lane = t & 63;
    const int wid  = t >> 6;
    if (lane == 0) ws[wid] = s;
    __syncthreads();
    if (t == 0) out[0] = ws[0] + ws[1] + ws[2] + ws[3];
}

extern "C" void kernel_launch(void* const* d_in, const int* in_sizes, int n_in,
                              void* d_out, int out_size, void* d_ws, size_t ws_size,
                              hipStream_t stream) {
    const float* x   = (const float*)d_in[0];
    const int*   tgt = (const int*)d_in[1];
    float*       out = (float*)d_out;
    float*       part = (float*)d_ws;    // 2048 floats = 8 KB of workspace

    fl_main<<<kGrid, kBlock, 0, stream>>>(x, tgt, part);
    fl_reduce<<<1, kBlock, 0, stream>>>(part, out);
}